// Round 1
// baseline (9154.649 us; speedup 1.0000x reference)
//
#include <hip/hip_runtime.h>
#include <hip/hip_bf16.h>
#include <math.h>

#define SLEN 2048
#define DDIM 512
#define BNUM 8
#define MTOT (BNUM * SLEN)   // 16384

// ---------------------------------------------------------------------------
// Kernel A: fused precompute GEMM  O = act(x @ [Wu|Wa|Wc|Wg]^T + bias)
// 128x128 tile, BK=8, 256 threads, 8x8 per-thread microtile, fp32.
// mode 0: sigmoid -> gbuf ; 1: cos/sin -> cosb/sinb ; 2: tanh -> cdbuf ;
// 3: sigmoid -> ogout (stored in d_out emitted region, consumed by emit kernel)
// ---------------------------------------------------------------------------
__global__ __launch_bounds__(256) void precompute_kernel(
    const float* __restrict__ x,
    const float* __restrict__ Wu, const float* __restrict__ bu,
    const float* __restrict__ Wa, const float* __restrict__ ba,
    const float* __restrict__ Wc, const float* __restrict__ bc,
    const float* __restrict__ Wg, const float* __restrict__ bg,
    float* __restrict__ gbuf, float* __restrict__ cosb,
    float* __restrict__ sinb, float* __restrict__ cdbuf,
    float* __restrict__ ogout)
{
    __shared__ float As[8][132];
    __shared__ float Bs[8][132];

    const int bn = blockIdx.x * 128;      // 0..1791 in steps of 128
    const int bm = blockIdx.y * 128;      // 0..16383

    const float* W; const float* bias; int mode; int dcol;
    if (bn < 512)       { W = Wu; bias = bu; mode = 0; dcol = bn; }
    else if (bn < 768)  { W = Wa; bias = ba; mode = 1; dcol = bn - 512; }
    else if (bn < 1280) { W = Wc; bias = bc; mode = 2; dcol = bn - 768; }
    else                { W = Wg; bias = bg; mode = 3; dcol = bn - 1280; }

    const int tid = threadIdx.x;
    const int tx = tid & 15, ty = tid >> 4;

    float acc[8][8];
    #pragma unroll
    for (int i = 0; i < 8; ++i)
        #pragma unroll
        for (int j = 0; j < 8; ++j) acc[i][j] = 0.f;

    for (int k0 = 0; k0 < DDIM; k0 += 8) {
        #pragma unroll
        for (int l = 0; l < 4; ++l) {
            int idx = l * 256 + tid;
            int kk = idx & 7, mm = idx >> 3;
            As[kk][mm] = x[(size_t)(bm + mm) * DDIM + k0 + kk];
            Bs[kk][mm] = W[(size_t)(dcol + mm) * DDIM + k0 + kk];
        }
        __syncthreads();
        #pragma unroll
        for (int kk = 0; kk < 8; ++kk) {
            float av[8], bv[8];
            *(float4*)&av[0] = *(const float4*)&As[kk][ty * 8];
            *(float4*)&av[4] = *(const float4*)&As[kk][ty * 8 + 4];
            *(float4*)&bv[0] = *(const float4*)&Bs[kk][tx * 8];
            *(float4*)&bv[4] = *(const float4*)&Bs[kk][tx * 8 + 4];
            #pragma unroll
            for (int i = 0; i < 8; ++i)
                #pragma unroll
                for (int j = 0; j < 8; ++j)
                    acc[i][j] = fmaf(av[i], bv[j], acc[i][j]);
        }
        __syncthreads();
    }

    #pragma unroll
    for (int i = 0; i < 8; ++i) {
        int m = bm + ty * 8 + i;
        #pragma unroll
        for (int j = 0; j < 8; ++j) {
            int n = dcol + tx * 8 + j;
            float v = acc[i][j] + bias[n];
            if (mode == 0) {
                gbuf[(size_t)m * 512 + n] = 1.f / (1.f + expf(-v));
            } else if (mode == 1) {
                cosb[(size_t)m * 256 + n] = cosf(v);
                sinb[(size_t)m * 256 + n] = sinf(v);
            } else if (mode == 2) {
                cdbuf[(size_t)m * 512 + n] = tanhf(v);
            } else {
                ogout[(size_t)m * 512 + n] = 1.f / (1.f + expf(-v));
            }
        }
    }
}

// ---------------------------------------------------------------------------
// Kernel B: sequential scan. 32 persistent WGs: batch b = wg&7 (same-XCD
// grouping), quarter q = wg>>3 owns output rows [q*128, q*128+128).
// Wt slice lives in registers (128 fp32/thread). Per-step cross-WG exchange
// via double-buffered global state + agent-scope spin barrier.
// ---------------------------------------------------------------------------
__global__ __launch_bounds__(512, 2) void scan_kernel(
    const float* __restrict__ Wt, const float* __restrict__ bt,
    const float* __restrict__ gbuf, const float* __restrict__ cosb,
    const float* __restrict__ sinb, const float* __restrict__ cdbuf,
    float* __restrict__ states, float* stateBuf,
    unsigned int* ctr, float* __restrict__ finalOut)
{
    const int wg = blockIdx.x;
    const int b = wg & 7, q = wg >> 3;
    const int tid = threadIdx.x;
    const int r = tid >> 2;          // 0..127 local output row
    const int kpart = tid & 3;
    const int o = q * 128 + r;       // global output dim
    const int kbase = kpart * 128;

    // Register-resident weight slice: Wt[o][kbase .. kbase+128)
    float w[128];
    {
        const float* wrow = Wt + (size_t)o * DDIM + kbase;
        #pragma unroll
        for (int j = 0; j < 32; ++j) {
            float4 v = *(const float4*)(wrow + 4 * j);
            w[4 * j + 0] = v.x; w[4 * j + 1] = v.y;
            w[4 * j + 2] = v.z; w[4 * j + 3] = v.w;
        }
    }
    const float btv = (kpart == 0) ? bt[o] : 0.f;

    __shared__ float lds_state[512];
    __shared__ float t_vals[128];

    const float* gptr = gbuf + (size_t)b * SLEN * 512;
    const float* cdp  = cdbuf + (size_t)b * SLEN * 512;
    const float* cp   = cosb + (size_t)b * SLEN * 256;
    const float* sp   = sinb + (size_t)b * SLEN * 256;
    float* stb = states + (size_t)b * SLEN * 512;
    unsigned int* mc = ctr + b * SLEN;

    for (int s = 0; s < SLEN; ++s) {
        if (s == 0) lds_state[tid] = 0.f;
        else        lds_state[tid] = stateBuf[((s & 1) * BNUM + b) * 512 + tid];
        __syncthreads();

        float p0 = 0.f, p1 = 0.f, p2 = 0.f, p3 = 0.f;
        const float* st = lds_state + kbase;
        #pragma unroll
        for (int j = 0; j < 32; ++j) {
            float4 sv = *(const float4*)(st + 4 * j);
            p0 = fmaf(w[4 * j + 0], sv.x, p0);
            p1 = fmaf(w[4 * j + 1], sv.y, p1);
            p2 = fmaf(w[4 * j + 2], sv.z, p2);
            p3 = fmaf(w[4 * j + 3], sv.w, p3);
        }
        float partial = (p0 + p1) + (p2 + p3);
        partial += __shfl_xor(partial, 1);
        partial += __shfl_xor(partial, 2);
        if (kpart == 0) t_vals[r] = partial + btv;
        __syncthreads();

        if (tid < 128) {
            int oo = q * 128 + tid;
            float tv = t_vals[tid];
            float tp = t_vals[tid ^ 1];
            float c  = cp[(size_t)s * 256 + (oo >> 1)];
            float sn = sp[(size_t)s * 256 + (oo >> 1)];
            float rot = (tid & 1) ? fmaf(tp, sn, tv * c)
                                  : fmaf(tv, c, -(tp * sn));
            float g  = gptr[(size_t)s * 512 + oo];
            float cd = cdp[(size_t)s * 512 + oo];
            float nxt = fmaf(g, rot, (1.f - g) * cd);
            stb[(size_t)s * 512 + oo] = nxt;
            stateBuf[(((s + 1) & 1) * BNUM + b) * 512 + oo] = nxt;
            if (s == SLEN - 1) finalOut[b * 512 + oo] = nxt;
        }
        __syncthreads();

        // per-batch barrier over its 4 WGs (agent scope: per-XCD L2s are
        // not coherent; fence writes back, acquire fence invalidates)
        if (tid == 0) {
            __threadfence();
            __hip_atomic_fetch_add(&mc[s], 1u, __ATOMIC_RELAXED,
                                   __HIP_MEMORY_SCOPE_AGENT);
            while (__hip_atomic_load(&mc[s], __ATOMIC_RELAXED,
                                     __HIP_MEMORY_SCOPE_AGENT) < 4u) {
                __builtin_amdgcn_s_sleep(1);
            }
            __threadfence();
        }
        __syncthreads();
    }
}

// ---------------------------------------------------------------------------
// Kernel C: emitted = og * (states @ Wo^T + bo). og was stored in-place in
// d_out by kernel A; each thread reads its element then overwrites it.
// ---------------------------------------------------------------------------
__global__ __launch_bounds__(256) void emit_kernel(
    const float* __restrict__ states, const float* __restrict__ Wo,
    const float* __restrict__ bo, float* __restrict__ out)
{
    __shared__ float As[8][132];
    __shared__ float Bs[8][132];

    const int bn = blockIdx.x * 128;
    const int bm = blockIdx.y * 128;
    const int tid = threadIdx.x;
    const int tx = tid & 15, ty = tid >> 4;

    float acc[8][8];
    #pragma unroll
    for (int i = 0; i < 8; ++i)
        #pragma unroll
        for (int j = 0; j < 8; ++j) acc[i][j] = 0.f;

    for (int k0 = 0; k0 < DDIM; k0 += 8) {
        #pragma unroll
        for (int l = 0; l < 4; ++l) {
            int idx = l * 256 + tid;
            int kk = idx & 7, mm = idx >> 3;
            As[kk][mm] = states[(size_t)(bm + mm) * DDIM + k0 + kk];
            Bs[kk][mm] = Wo[(size_t)(bn + mm) * DDIM + k0 + kk];
        }
        __syncthreads();
        #pragma unroll
        for (int kk = 0; kk < 8; ++kk) {
            float av[8], bv[8];
            *(float4*)&av[0] = *(const float4*)&As[kk][ty * 8];
            *(float4*)&av[4] = *(const float4*)&As[kk][ty * 8 + 4];
            *(float4*)&bv[0] = *(const float4*)&Bs[kk][tx * 8];
            *(float4*)&bv[4] = *(const float4*)&Bs[kk][tx * 8 + 4];
            #pragma unroll
            for (int i = 0; i < 8; ++i)
                #pragma unroll
                for (int j = 0; j < 8; ++j)
                    acc[i][j] = fmaf(av[i], bv[j], acc[i][j]);
        }
        __syncthreads();
    }

    #pragma unroll
    for (int i = 0; i < 8; ++i) {
        int m = bm + ty * 8 + i;
        #pragma unroll
        for (int j = 0; j < 8; ++j) {
            int n = bn + tx * 8 + j;
            size_t idx = (size_t)m * 512 + n;
            float og = out[idx];
            out[idx] = og * (acc[i][j] + bo[n]);
        }
    }
}

// ---------------------------------------------------------------------------
extern "C" void kernel_launch(void* const* d_in, const int* in_sizes, int n_in,
                              void* d_out, int out_size, void* d_ws, size_t ws_size,
                              hipStream_t stream)
{
    const float* x  = (const float*)d_in[0];
    const float* Wu = (const float*)d_in[1];
    const float* bu = (const float*)d_in[2];
    const float* Wt = (const float*)d_in[3];
    const float* bt = (const float*)d_in[4];
    const float* Wa = (const float*)d_in[5];
    const float* ba = (const float*)d_in[6];
    const float* Wc = (const float*)d_in[7];
    const float* bc = (const float*)d_in[8];
    const float* Wg = (const float*)d_in[9];
    const float* bg = (const float*)d_in[10];
    const float* Wo = (const float*)d_in[11];
    const float* bo = (const float*)d_in[12];
    float* out = (float*)d_out;

    // workspace layout (floats)
    float* wsf    = (float*)d_ws;
    float* gbuf   = wsf;                               // 16384*512
    float* cosb   = gbuf   + (size_t)MTOT * 512;       // 16384*256
    float* sinb   = cosb   + (size_t)MTOT * 256;       // 16384*256
    float* cdbuf  = sinb   + (size_t)MTOT * 256;       // 16384*512
    float* states = cdbuf  + (size_t)MTOT * 512;       // 16384*512
    float* stateBuf = states + (size_t)MTOT * 512;     // 2*8*512
    unsigned int* ctr = (unsigned int*)(stateBuf + 2 * BNUM * 512); // 8*2048

    hipMemsetAsync(ctr, 0, (size_t)BNUM * SLEN * sizeof(unsigned int), stream);

    precompute_kernel<<<dim3(14, 128), 256, 0, stream>>>(
        x, Wu, bu, Wa, ba, Wc, bc, Wg, bg,
        gbuf, cosb, sinb, cdbuf, out /* og staged in emitted region */);

    scan_kernel<<<32, 512, 0, stream>>>(
        Wt, bt, gbuf, cosb, sinb, cdbuf,
        states, stateBuf, ctr, out + (size_t)MTOT * 512);

    emit_kernel<<<dim3(4, 128), 256, 0, stream>>>(states, Wo, bo, out);
}

// Round 4
// 6959.136 us; speedup vs baseline: 1.3155x; 1.3155x over previous
//
#include <hip/hip_runtime.h>
#include <hip/hip_bf16.h>
#include <math.h>

#define SLEN 2048
#define DDIM 512
#define BNUM 8
#define MTOT (BNUM * SLEN)   // 16384

// ---------------------------------------------------------------------------
// Agent-scope (device-coherent) 8-byte access helpers. `sc1` = agent scope
// on gfx94x/gfx950: bypasses the non-coherent per-XCD caches so the
// coherence point is the device LLC. ALL writers and readers of the tag
// buffer use exactly this path — single coherence point, no stale copies.
// ---------------------------------------------------------------------------
__device__ __forceinline__ uint2 ld_u64_agent(const uint2* p) {
    uint2 v;
    asm volatile("global_load_dwordx2 %0, %1, off sc1\n\ts_waitcnt vmcnt(0)"
                 : "=v"(v) : "v"(p) : "memory");
    return v;
}
__device__ __forceinline__ void st_u64_agent(uint2* p, uint2 v) {
    asm volatile("global_store_dwordx2 %0, %1, off sc1"
                 :: "v"(p), "v"(v) : "memory");
}

// ---------------------------------------------------------------------------
// Kernel 0: clear the tag buffer through the SAME cache-bypassing path the
// scan uses. (hipMemsetAsync wrote via the cached path: its data could sit
// dirty in one XCD's L2 while pollers read the LLC -> stale tags from the
// previous graph replay -> exact-match collision at step 2047. This kernel
// is the fix.)
// ---------------------------------------------------------------------------
__global__ __launch_bounds__(512) void clear_tags_kernel(uint2* stateTag)
{
    int i = blockIdx.x * 512 + threadIdx.x;
    uint2 z; z.x = 0u; z.y = 0u;
    st_u64_agent(&stateTag[i], z);
}

// ---------------------------------------------------------------------------
// Kernel A: fused precompute GEMM  O = act(x @ [Wu|Wa|Wc|Wg]^T + bias)
// ---------------------------------------------------------------------------
__global__ __launch_bounds__(256) void precompute_kernel(
    const float* __restrict__ x,
    const float* __restrict__ Wu, const float* __restrict__ bu,
    const float* __restrict__ Wa, const float* __restrict__ ba,
    const float* __restrict__ Wc, const float* __restrict__ bc,
    const float* __restrict__ Wg, const float* __restrict__ bg,
    float* __restrict__ gbuf, float* __restrict__ cosb,
    float* __restrict__ sinb, float* __restrict__ cdbuf,
    float* __restrict__ ogout)
{
    __shared__ float As[8][132];
    __shared__ float Bs[8][132];

    const int bn = blockIdx.x * 128;      // 0..1791 in steps of 128
    const int bm = blockIdx.y * 128;      // 0..16383

    const float* W; const float* bias; int mode; int dcol;
    if (bn < 512)       { W = Wu; bias = bu; mode = 0; dcol = bn; }
    else if (bn < 768)  { W = Wa; bias = ba; mode = 1; dcol = bn - 512; }
    else if (bn < 1280) { W = Wc; bias = bc; mode = 2; dcol = bn - 768; }
    else                { W = Wg; bias = bg; mode = 3; dcol = bn - 1280; }

    const int tid = threadIdx.x;
    const int tx = tid & 15, ty = tid >> 4;

    float acc[8][8];
    #pragma unroll
    for (int i = 0; i < 8; ++i)
        #pragma unroll
        for (int j = 0; j < 8; ++j) acc[i][j] = 0.f;

    for (int k0 = 0; k0 < DDIM; k0 += 8) {
        #pragma unroll
        for (int l = 0; l < 4; ++l) {
            int idx = l * 256 + tid;
            int kk = idx & 7, mm = idx >> 3;
            As[kk][mm] = x[(size_t)(bm + mm) * DDIM + k0 + kk];
            Bs[kk][mm] = W[(size_t)(dcol + mm) * DDIM + k0 + kk];
        }
        __syncthreads();
        #pragma unroll
        for (int kk = 0; kk < 8; ++kk) {
            float av[8], bv[8];
            *(float4*)&av[0] = *(const float4*)&As[kk][ty * 8];
            *(float4*)&av[4] = *(const float4*)&As[kk][ty * 8 + 4];
            *(float4*)&bv[0] = *(const float4*)&Bs[kk][tx * 8];
            *(float4*)&bv[4] = *(const float4*)&Bs[kk][tx * 8 + 4];
            #pragma unroll
            for (int i = 0; i < 8; ++i)
                #pragma unroll
                for (int j = 0; j < 8; ++j)
                    acc[i][j] = fmaf(av[i], bv[j], acc[i][j]);
        }
        __syncthreads();
    }

    #pragma unroll
    for (int i = 0; i < 8; ++i) {
        int m = bm + ty * 8 + i;
        #pragma unroll
        for (int j = 0; j < 8; ++j) {
            int n = dcol + tx * 8 + j;
            float v = acc[i][j] + bias[n];
            if (mode == 0) {
                gbuf[(size_t)m * 512 + n] = 1.f / (1.f + expf(-v));
            } else if (mode == 1) {
                cosb[(size_t)m * 256 + n] = cosf(v);
                sinb[(size_t)m * 256 + n] = sinf(v);
            } else if (mode == 2) {
                cdbuf[(size_t)m * 512 + n] = tanhf(v);
            } else {
                ogout[(size_t)m * 512 + n] = 1.f / (1.f + expf(-v));
            }
        }
    }
}

// ---------------------------------------------------------------------------
// Kernel B: sequential scan. 32 persistent WGs: batch b = wg&7, quarter
// q = wg>>3 owns output rows [q*128, q*128+128). Wt slice in registers.
// Cross-WG exchange: generation-tagged double buffer, agent-scope 8B
// stores/loads (single coherence point). Element = {f32 bits, tag=s+1}.
// Backpressure: a WG can only overwrite a parity slot (tag s+3) after it
// consumed all peers' tag s+2, which peers publish only after they consumed
// tag s+1 — so readers of tag s+1 are always done before the overwrite.
// ---------------------------------------------------------------------------
__global__ __launch_bounds__(512, 2) void scan_kernel(
    const float* __restrict__ Wt, const float* __restrict__ bt,
    const float* __restrict__ gbuf, const float* __restrict__ cosb,
    const float* __restrict__ sinb, const float* __restrict__ cdbuf,
    float* __restrict__ states, uint2* stateTag,
    float* __restrict__ finalOut)
{
    const int wg = blockIdx.x;
    const int b = wg & 7, q = wg >> 3;
    const int tid = threadIdx.x;
    const int r = tid >> 2;          // 0..127 local output row
    const int kpart = tid & 3;
    const int o = q * 128 + r;       // global output dim
    const int kbase = kpart * 128;

    // Register-resident weight slice: Wt[o][kbase .. kbase+128)
    float w[128];
    {
        const float* wrow = Wt + (size_t)o * DDIM + kbase;
        #pragma unroll
        for (int j = 0; j < 32; ++j) {
            float4 v = *(const float4*)(wrow + 4 * j);
            w[4 * j + 0] = v.x; w[4 * j + 1] = v.y;
            w[4 * j + 2] = v.z; w[4 * j + 3] = v.w;
        }
    }
    const float btv = (kpart == 0) ? bt[o] : 0.f;

    __shared__ float lds_state[512];
    __shared__ float t_vals[128];

    const float* gptr = gbuf + (size_t)b * SLEN * 512;
    const float* cdp  = cdbuf + (size_t)b * SLEN * 512;
    const float* cp   = cosb + (size_t)b * SLEN * 256;
    const float* sp   = sinb + (size_t)b * SLEN * 256;
    float* stb = states + (size_t)b * SLEN * 512;

    for (int s = 0; s < SLEN; ++s) {
        // ---- prefetch this step's gate data (independent of state; issued
        //      before the volatile poll asm so they're on the wire early) ----
        float g_ = 0.f, cd_ = 0.f, c_ = 0.f, sn_ = 0.f;
        if (tid < 128) {
            int oo = q * 128 + tid;
            g_  = gptr[(size_t)s * 512 + oo];
            cd_ = cdp[(size_t)s * 512 + oo];
            c_  = cp[(size_t)s * 256 + (oo >> 1)];
            sn_ = sp[(size_t)s * 256 + (oo >> 1)];
        }

        // ---- obtain S_s into LDS ----
        if (s == 0) {
            lds_state[tid] = 0.f;
        } else {
            int j = tid >> 7;                 // which quarter this lane fills
            if (j != q) {                     // own quarter already in LDS
                const uint2* p = stateTag +
                    ((size_t)(s & 1) * BNUM + b) * 512 + tid;
                uint2 u; int guard = 0;
                do { u = ld_u64_agent(p); }
                while (u.y != (unsigned)s && ++guard < (1 << 18));
                lds_state[tid] = __uint_as_float(u.x);
            }
        }
        __syncthreads();

        // ---- matvec t = Wt[o,:] . S_s ----
        float p0 = 0.f, p1 = 0.f, p2 = 0.f, p3 = 0.f;
        const float* st = lds_state + kbase;
        #pragma unroll
        for (int j = 0; j < 32; ++j) {
            float4 sv = *(const float4*)(st + 4 * j);
            p0 = fmaf(w[4 * j + 0], sv.x, p0);
            p1 = fmaf(w[4 * j + 1], sv.y, p1);
            p2 = fmaf(w[4 * j + 2], sv.z, p2);
            p3 = fmaf(w[4 * j + 3], sv.w, p3);
        }
        float partial = (p0 + p1) + (p2 + p3);
        partial += __shfl_xor(partial, 1);
        partial += __shfl_xor(partial, 2);
        if (kpart == 0) t_vals[r] = partial + btv;
        __syncthreads();

        // ---- rotate, gate, publish S_{s+1} (publish store FIRST) ----
        if (tid < 128) {
            int oo = q * 128 + tid;
            float tv = t_vals[tid];
            float tp = t_vals[tid ^ 1];
            float rot = (tid & 1) ? fmaf(tp, sn_, tv * c_)
                                  : fmaf(tv, c_, -(tp * sn_));
            float nxt = fmaf(g_, rot, (1.f - g_) * cd_);
            uint2 u; u.x = __float_as_uint(nxt); u.y = (unsigned)(s + 1);
            st_u64_agent(&stateTag[((size_t)((s + 1) & 1) * BNUM + b) * 512 + oo], u);
            stb[(size_t)s * 512 + oo] = nxt;          // for emit kernel
            lds_state[oo] = nxt;                      // own quarter, next step
            if (s == SLEN - 1) finalOut[b * 512 + oo] = nxt;
        }
        // No barrier needed: next iteration writes only non-own quarters of
        // lds_state (disjoint), and t_vals is rewritten only after the next
        // __syncthreads().
    }
}

// ---------------------------------------------------------------------------
// Kernel C: emitted = og * (states @ Wo^T + bo). og staged in d_out by A.
// ---------------------------------------------------------------------------
__global__ __launch_bounds__(256) void emit_kernel(
    const float* __restrict__ states, const float* __restrict__ Wo,
    const float* __restrict__ bo, float* __restrict__ out)
{
    __shared__ float As[8][132];
    __shared__ float Bs[8][132];

    const int bn = blockIdx.x * 128;
    const int bm = blockIdx.y * 128;
    const int tid = threadIdx.x;
    const int tx = tid & 15, ty = tid >> 4;

    float acc[8][8];
    #pragma unroll
    for (int i = 0; i < 8; ++i)
        #pragma unroll
        for (int j = 0; j < 8; ++j) acc[i][j] = 0.f;

    for (int k0 = 0; k0 < DDIM; k0 += 8) {
        #pragma unroll
        for (int l = 0; l < 4; ++l) {
            int idx = l * 256 + tid;
            int kk = idx & 7, mm = idx >> 3;
            As[kk][mm] = states[(size_t)(bm + mm) * DDIM + k0 + kk];
            Bs[kk][mm] = Wo[(size_t)(bn + mm) * DDIM + k0 + kk];
        }
        __syncthreads();
        #pragma unroll
        for (int kk = 0; kk < 8; ++kk) {
            float av[8], bv[8];
            *(float4*)&av[0] = *(const float4*)&As[kk][ty * 8];
            *(float4*)&av[4] = *(const float4*)&As[kk][ty * 8 + 4];
            *(float4*)&bv[0] = *(const float4*)&Bs[kk][tx * 8];
            *(float4*)&bv[4] = *(const float4*)&Bs[kk][tx * 8 + 4];
            #pragma unroll
            for (int i = 0; i < 8; ++i)
                #pragma unroll
                for (int j = 0; j < 8; ++j)
                    acc[i][j] = fmaf(av[i], bv[j], acc[i][j]);
        }
        __syncthreads();
    }

    #pragma unroll
    for (int i = 0; i < 8; ++i) {
        int m = bm + ty * 8 + i;
        #pragma unroll
        for (int j = 0; j < 8; ++j) {
            int n = bn + tx * 8 + j;
            size_t idx = (size_t)m * 512 + n;
            float og = out[idx];
            out[idx] = og * (acc[i][j] + bo[n]);
        }
    }
}

// ---------------------------------------------------------------------------
extern "C" void kernel_launch(void* const* d_in, const int* in_sizes, int n_in,
                              void* d_out, int out_size, void* d_ws, size_t ws_size,
                              hipStream_t stream)
{
    const float* x  = (const float*)d_in[0];
    const float* Wu = (const float*)d_in[1];
    const float* bu = (const float*)d_in[2];
    const float* Wt = (const float*)d_in[3];
    const float* bt = (const float*)d_in[4];
    const float* Wa = (const float*)d_in[5];
    const float* ba = (const float*)d_in[6];
    const float* Wc = (const float*)d_in[7];
    const float* bc = (const float*)d_in[8];
    const float* Wg = (const float*)d_in[9];
    const float* bg = (const float*)d_in[10];
    const float* Wo = (const float*)d_in[11];
    const float* bo = (const float*)d_in[12];
    float* out = (float*)d_out;

    // workspace layout (floats)
    float* wsf    = (float*)d_ws;
    float* gbuf   = wsf;                               // 16384*512
    float* cosb   = gbuf   + (size_t)MTOT * 512;       // 16384*256
    float* sinb   = cosb   + (size_t)MTOT * 256;       // 16384*256
    float* cdbuf  = sinb   + (size_t)MTOT * 256;       // 16384*512
    float* states = cdbuf  + (size_t)MTOT * 512;       // 16384*512
    uint2* stateTag = (uint2*)(states + (size_t)MTOT * 512); // 2*8*512 uint2

    // clear tags through the agent-scope path (same path the scan uses).
    clear_tags_kernel<<<16, 512, 0, stream>>>(stateTag);

    precompute_kernel<<<dim3(14, 128), 256, 0, stream>>>(
        x, Wu, bu, Wa, ba, Wc, bc, Wg, bg,
        gbuf, cosb, sinb, cdbuf, out /* og staged in emitted region */);

    scan_kernel<<<32, 512, 0, stream>>>(
        Wt, bt, gbuf, cosb, sinb, cdbuf,
        states, stateTag, out + (size_t)MTOT * 512);

    emit_kernel<<<dim3(4, 128), 256, 0, stream>>>(states, Wo, bo, out);
}

// Round 5
// 4683.990 us; speedup vs baseline: 1.9545x; 1.4857x over previous
//
#include <hip/hip_runtime.h>
#include <hip/hip_bf16.h>
#include <math.h>

#define SLEN 2048
#define DDIM 512
#define BNUM 8
#define MTOT (BNUM * SLEN)   // 16384

typedef float f32x4 __attribute__((ext_vector_type(4)));

// ---------------------------------------------------------------------------
// Agent-scope (device-coherent) 8-byte access helpers. `sc1` bypasses the
// non-coherent per-XCD caches; coherence point = device LLC. ALL writers and
// readers of the tag buffer use exactly this path (round-3 lesson: a single
// coherence point, including the clearing kernel).
// ---------------------------------------------------------------------------
__device__ __forceinline__ uint2 ld_u64_agent(const uint2* p) {
    uint2 v;
    asm volatile("global_load_dwordx2 %0, %1, off sc1\n\ts_waitcnt vmcnt(0)"
                 : "=v"(v) : "v"(p) : "memory");
    return v;
}
__device__ __forceinline__ void st_u64_agent(uint2* p, uint2 v) {
    asm volatile("global_store_dwordx2 %0, %1, off sc1"
                 :: "v"(p), "v"(v) : "memory");
}

// ---------------------------------------------------------------------------
// Kernel 0: clear tag buffer through the SAME sc1 path the scan uses.
// ---------------------------------------------------------------------------
__global__ __launch_bounds__(512) void clear_tags_kernel(uint2* stateTag)
{
    int i = blockIdx.x * 512 + threadIdx.x;
    uint2 z; z.x = 0u; z.y = 0u;
    st_u64_agent(&stateTag[i], z);
}

// ---------------------------------------------------------------------------
// Kernel A: fused precompute GEMM  O = act(x @ [Wu|Wa|Wc|Wg]^T + bias)
// ---------------------------------------------------------------------------
__global__ __launch_bounds__(256) void precompute_kernel(
    const float* __restrict__ x,
    const float* __restrict__ Wu, const float* __restrict__ bu,
    const float* __restrict__ Wa, const float* __restrict__ ba,
    const float* __restrict__ Wc, const float* __restrict__ bc,
    const float* __restrict__ Wg, const float* __restrict__ bg,
    float* __restrict__ gbuf, float* __restrict__ cosb,
    float* __restrict__ sinb, float* __restrict__ cdbuf,
    float* __restrict__ ogout)
{
    __shared__ float As[8][132];
    __shared__ float Bs[8][132];

    const int bn = blockIdx.x * 128;      // 0..1791 in steps of 128
    const int bm = blockIdx.y * 128;      // 0..16383

    const float* W; const float* bias; int mode; int dcol;
    if (bn < 512)       { W = Wu; bias = bu; mode = 0; dcol = bn; }
    else if (bn < 768)  { W = Wa; bias = ba; mode = 1; dcol = bn - 512; }
    else if (bn < 1280) { W = Wc; bias = bc; mode = 2; dcol = bn - 768; }
    else                { W = Wg; bias = bg; mode = 3; dcol = bn - 1280; }

    const int tid = threadIdx.x;
    const int tx = tid & 15, ty = tid >> 4;

    float acc[8][8];
    #pragma unroll
    for (int i = 0; i < 8; ++i)
        #pragma unroll
        for (int j = 0; j < 8; ++j) acc[i][j] = 0.f;

    for (int k0 = 0; k0 < DDIM; k0 += 8) {
        #pragma unroll
        for (int l = 0; l < 4; ++l) {
            int idx = l * 256 + tid;
            int kk = idx & 7, mm = idx >> 3;
            As[kk][mm] = x[(size_t)(bm + mm) * DDIM + k0 + kk];
            Bs[kk][mm] = W[(size_t)(dcol + mm) * DDIM + k0 + kk];
        }
        __syncthreads();
        #pragma unroll
        for (int kk = 0; kk < 8; ++kk) {
            float av[8], bv[8];
            *(float4*)&av[0] = *(const float4*)&As[kk][ty * 8];
            *(float4*)&av[4] = *(const float4*)&As[kk][ty * 8 + 4];
            *(float4*)&bv[0] = *(const float4*)&Bs[kk][tx * 8];
            *(float4*)&bv[4] = *(const float4*)&Bs[kk][tx * 8 + 4];
            #pragma unroll
            for (int i = 0; i < 8; ++i)
                #pragma unroll
                for (int j = 0; j < 8; ++j)
                    acc[i][j] = fmaf(av[i], bv[j], acc[i][j]);
        }
        __syncthreads();
    }

    #pragma unroll
    for (int i = 0; i < 8; ++i) {
        int m = bm + ty * 8 + i;
        #pragma unroll
        for (int j = 0; j < 8; ++j) {
            int n = dcol + tx * 8 + j;
            float v = acc[i][j] + bias[n];
            if (mode == 0) {
                gbuf[(size_t)m * 512 + n] = 1.f / (1.f + expf(-v));
            } else if (mode == 1) {
                cosb[(size_t)m * 256 + n] = cosf(v);
                sinb[(size_t)m * 256 + n] = sinf(v);
            } else if (mode == 2) {
                cdbuf[(size_t)m * 512 + n] = tanhf(v);
            } else {
                ogout[(size_t)m * 512 + n] = 1.f / (1.f + expf(-v));
            }
        }
    }
}

// ---------------------------------------------------------------------------
// Kernel B: sequential scan. 32 persistent WGs of 1024 threads: batch
// b = wg&7, quarter q = wg>>3 owns output rows [q*128, q*128+128).
// Per thread: row r = tid>>3, k-part kpart = tid&7 -> 64 fp32 weights in
// 16 f32x4 VGPRs (64 regs; cap is 128 at 4 waves/SIMD -> truly resident).
// LDS state padded [8][68]: the 8 kpart segments map to disjoint bank
// quads -> conflict-free ds_read_b128 broadcast.
// Gates for step s+1 are prefetched into registers during step s.
// Cross-WG exchange: generation-tagged double buffer via sc1 (round 4's
// proven protocol, unchanged).
// ---------------------------------------------------------------------------
__global__ __launch_bounds__(1024, 4) void scan_kernel(
    const float* __restrict__ Wt, const float* __restrict__ bt,
    const float* __restrict__ gbuf, const float* __restrict__ cosb,
    const float* __restrict__ sinb, const float* __restrict__ cdbuf,
    float* __restrict__ states, uint2* stateTag,
    float* __restrict__ finalOut)
{
    const int wg = blockIdx.x;
    const int b = wg & 7, q = wg >> 3;
    const int tid = threadIdx.x;
    const int r = tid >> 3;          // 0..127 local output row
    const int kpart = tid & 7;       // 0..7
    const int o = q * 128 + r;       // global output dim
    const int kbase = kpart * 64;

    // Register-resident weight slice: Wt[o][kbase .. kbase+64)
    f32x4 w[16];
    {
        const float* wrow = Wt + (size_t)o * DDIM + kbase;
        #pragma unroll
        for (int j = 0; j < 16; ++j)
            w[j] = *(const f32x4*)(wrow + 4 * j);
    }
    const float btv = (kpart == 0) ? bt[o] : 0.f;

    __shared__ float lds8[8][68];    // padded: segment p at row p
    __shared__ float t_vals[128];

    const float* pg  = gbuf + (size_t)b * SLEN * 512;
    const float* pcd = cdbuf + (size_t)b * SLEN * 512;
    const float* pc  = cosb + (size_t)b * SLEN * 256;
    const float* psn = sinb + (size_t)b * SLEN * 256;
    float* stb = states + (size_t)b * SLEN * 512;

    // gate double-buffer registers; prologue loads step 0
    float gN = 0.f, cdN = 0.f, cN = 0.f, snN = 0.f;
    if (tid < 128) {
        int oo = q * 128 + tid;
        gN  = pg [(size_t)0 * 512 + oo];
        cdN = pcd[(size_t)0 * 512 + oo];
        cN  = pc [(size_t)0 * 256 + (oo >> 1)];
        snN = psn[(size_t)0 * 256 + (oo >> 1)];
    }

    for (int s = 0; s < SLEN; ++s) {
        float gC = gN, cdC = cdN, cC = cN, snC = snN;

        // ---- obtain S_s into LDS (padded layout) ----
        if (s == 0) {
            if (tid < 512) lds8[tid >> 6][tid & 63] = 0.f;
        } else {
            if (tid < 512 && (tid >> 7) != q) {   // own quarter already fresh
                const uint2* p = stateTag +
                    ((size_t)(s & 1) * BNUM + b) * 512 + tid;
                uint2 u; int guard = 0;
                do { u = ld_u64_agent(p); }
                while (u.y != (unsigned)s && ++guard < (1 << 16));
                lds8[tid >> 6][tid & 63] = __uint_as_float(u.x);
            }
        }
        __syncthreads();

        // ---- prefetch NEXT step's gates (overlaps matvec etc.) ----
        if (tid < 128) {
            int sp1 = (s + 1) & (SLEN - 1);       // wrap harmlessly at end
            int oo = q * 128 + tid;
            gN  = pg [(size_t)sp1 * 512 + oo];
            cdN = pcd[(size_t)sp1 * 512 + oo];
            cN  = pc [(size_t)sp1 * 256 + (oo >> 1)];
            snN = psn[(size_t)sp1 * 256 + (oo >> 1)];
        }

        // ---- matvec t = Wt[o,:] . S_s (64 MACs/thread) ----
        float p0 = 0.f, p1 = 0.f, p2 = 0.f, p3 = 0.f;
        const float* st = &lds8[kpart][0];
        #pragma unroll
        for (int j = 0; j < 16; ++j) {
            f32x4 sv = *(const f32x4*)(st + 4 * j);
            p0 = fmaf(w[j].x, sv.x, p0);
            p1 = fmaf(w[j].y, sv.y, p1);
            p2 = fmaf(w[j].z, sv.z, p2);
            p3 = fmaf(w[j].w, sv.w, p3);
        }
        float partial = (p0 + p1) + (p2 + p3);
        partial += __shfl_xor(partial, 1);
        partial += __shfl_xor(partial, 2);
        partial += __shfl_xor(partial, 4);
        if (kpart == 0) t_vals[r] = partial + btv;
        __syncthreads();

        // ---- rotate, gate, publish S_{s+1} (publish store FIRST) ----
        if (tid < 128) {
            int oo = q * 128 + tid;
            float tv = t_vals[tid];
            float tp = t_vals[tid ^ 1];
            float rot = (tid & 1) ? fmaf(tp, snC, tv * cC)
                                  : fmaf(tv, cC, -(tp * snC));
            float nxt = fmaf(gC, rot, (1.f - gC) * cdC);
            uint2 u; u.x = __float_as_uint(nxt); u.y = (unsigned)(s + 1);
            st_u64_agent(&stateTag[((size_t)((s + 1) & 1) * BNUM + b) * 512 + oo], u);
            stb[(size_t)s * 512 + oo] = nxt;              // for emit kernel
            int e = oo;                                   // own-quarter LDS update
            lds8[e >> 6][e & 63] = nxt;
            if (s == SLEN - 1) finalOut[b * 512 + oo] = nxt;
        }
        // No barrier needed here: next iteration's fill writes only
        // non-own segments (disjoint from the own-quarter update above),
        // and all step-s LDS reads completed before the t_vals barrier.
    }
}

// ---------------------------------------------------------------------------
// Kernel C: emitted = og * (states @ Wo^T + bo). og staged in d_out by A.
// ---------------------------------------------------------------------------
__global__ __launch_bounds__(256) void emit_kernel(
    const float* __restrict__ states, const float* __restrict__ Wo,
    const float* __restrict__ bo, float* __restrict__ out)
{
    __shared__ float As[8][132];
    __shared__ float Bs[8][132];

    const int bn = blockIdx.x * 128;
    const int bm = blockIdx.y * 128;
    const int tid = threadIdx.x;
    const int tx = tid & 15, ty = tid >> 4;

    float acc[8][8];
    #pragma unroll
    for (int i = 0; i < 8; ++i)
        #pragma unroll
        for (int j = 0; j < 8; ++j) acc[i][j] = 0.f;

    for (int k0 = 0; k0 < DDIM; k0 += 8) {
        #pragma unroll
        for (int l = 0; l < 4; ++l) {
            int idx = l * 256 + tid;
            int kk = idx & 7, mm = idx >> 3;
            As[kk][mm] = states[(size_t)(bm + mm) * DDIM + k0 + kk];
            Bs[kk][mm] = Wo[(size_t)(bn + mm) * DDIM + k0 + kk];
        }
        __syncthreads();
        #pragma unroll
        for (int kk = 0; kk < 8; ++kk) {
            float av[8], bv[8];
            *(float4*)&av[0] = *(const float4*)&As[kk][ty * 8];
            *(float4*)&av[4] = *(const float4*)&As[kk][ty * 8 + 4];
            *(float4*)&bv[0] = *(const float4*)&Bs[kk][tx * 8];
            *(float4*)&bv[4] = *(const float4*)&Bs[kk][tx * 8 + 4];
            #pragma unroll
            for (int i = 0; i < 8; ++i)
                #pragma unroll
                for (int j = 0; j < 8; ++j)
                    acc[i][j] = fmaf(av[i], bv[j], acc[i][j]);
        }
        __syncthreads();
    }

    #pragma unroll
    for (int i = 0; i < 8; ++i) {
        int m = bm + ty * 8 + i;
        #pragma unroll
        for (int j = 0; j < 8; ++j) {
            int n = bn + tx * 8 + j;
            size_t idx = (size_t)m * 512 + n;
            float og = out[idx];
            out[idx] = og * (acc[i][j] + bo[n]);
        }
    }
}

// ---------------------------------------------------------------------------
extern "C" void kernel_launch(void* const* d_in, const int* in_sizes, int n_in,
                              void* d_out, int out_size, void* d_ws, size_t ws_size,
                              hipStream_t stream)
{
    const float* x  = (const float*)d_in[0];
    const float* Wu = (const float*)d_in[1];
    const float* bu = (const float*)d_in[2];
    const float* Wt = (const float*)d_in[3];
    const float* bt = (const float*)d_in[4];
    const float* Wa = (const float*)d_in[5];
    const float* ba = (const float*)d_in[6];
    const float* Wc = (const float*)d_in[7];
    const float* bc = (const float*)d_in[8];
    const float* Wg = (const float*)d_in[9];
    const float* bg = (const float*)d_in[10];
    const float* Wo = (const float*)d_in[11];
    const float* bo = (const float*)d_in[12];
    float* out = (float*)d_out;

    // workspace layout (floats)
    float* wsf    = (float*)d_ws;
    float* gbuf   = wsf;                               // 16384*512
    float* cosb   = gbuf   + (size_t)MTOT * 512;       // 16384*256
    float* sinb   = cosb   + (size_t)MTOT * 256;       // 16384*256
    float* cdbuf  = sinb   + (size_t)MTOT * 256;       // 16384*512
    float* states = cdbuf  + (size_t)MTOT * 512;       // 16384*512
    uint2* stateTag = (uint2*)(states + (size_t)MTOT * 512); // 2*8*512 uint2

    // clear tags through the sc1 path (same path the scan uses).
    clear_tags_kernel<<<16, 512, 0, stream>>>(stateTag);

    precompute_kernel<<<dim3(14, 128), 256, 0, stream>>>(
        x, Wu, bu, Wa, ba, Wc, bc, Wg, bg,
        gbuf, cosb, sinb, cdbuf, out /* og staged in emitted region */);

    scan_kernel<<<32, 1024, 0, stream>>>(
        Wt, bt, gbuf, cosb, sinb, cdbuf,
        states, stateTag, out + (size_t)MTOT * 512);

    emit_kernel<<<dim3(4, 128), 256, 0, stream>>>(states, Wo, bo, out);
}